// Round 5
// baseline (230.167 us; speedup 1.0000x reference)
//
#include <hip/hip_runtime.h>
#include <math.h>

#define BS  128
#define OBJ 512
#define RNN 1024
#define HID 512

// Merge two wave-wide partial sums (butterfly tree step).
__device__ __forceinline__ float combine2(float x, float y, int w) {
    int lane = threadIdx.x & 63;
    float send  = (lane & w) ? x : y;
    float other = __shfl_xor(send, w, 64);
    float keep  = (lane & w) ? y : x;
    return keep + other;
}

__device__ __forceinline__ float dot4(float4 a, float4 b, float s) {
    s = fmaf(a.x, b.x, s);
    s = fmaf(a.y, b.y, s);
    s = fmaf(a.z, b.z, s);
    s = fmaf(a.w, b.w, s);
    return s;
}

// One block per batch b. 1024 threads = 16 waves.
// Phase 1: att_h[b,:] = h[b,:] @ W^T  -> LDS, prescaled: hs[j]=(att_h+bias)*C
// Phase 2: scores -> e = exp(score)*mask -> LDS ebuf + LDS-atomic sum
//          score = sum(w) - 2*sum(w * rcp(exp2(C*f + hs) + 1)),  C = 2*log2(e)
//          (tanh(x) = 1 - 2/(1+e^{2x});  b_alpha cancels in softmax;
//           |score| <= sum|w_alpha| ~ 18 so no max-shift needed in fp32)
// Phase 3: out = ebuf / sum
__global__ __launch_bounds__(1024, 4) void fused1(
    const float* __restrict__ h, const float* __restrict__ att_feats,
    const int* __restrict__ masks, const float* __restrict__ W,
    const float* __restrict__ b_h2att, const float* __restrict__ w_alpha,
    float* __restrict__ out)
{
    __shared__ float lds_hs[HID];   // (att_h + bias) * C
    __shared__ float ebuf[OBJ];     // exp(score)*mask
    __shared__ float lds_sum;

    const int b    = blockIdx.x;
    const int lane = threadIdx.x & 63;
    const int wv   = threadIdx.x >> 6;        // 0..15
    const float C  = 2.8853900817779268f;     // 2*log2(e)

    if (threadIdx.x == 0) lds_sum = 0.0f;

    // ---------------- Phase 1: att_h row b -> LDS ----------------
    {
        const float4* h4 = (const float4*)h;  // row stride 256 float4
        const float4* W4 = (const float4*)W;  // row stride 256 float4

        float4 ha[4];
#pragma unroll
        for (int i = 0; i < 4; ++i) ha[i] = h4[b * 256 + i * 64 + lane];

#pragma unroll
        for (int g = 0; g < 4; ++g) {         // wave covers 32 j-rows
            const int j0 = wv * 32 + g * 8;
            float acc[8];
#pragma unroll
            for (int jj = 0; jj < 8; ++jj) {
                const int wbase = (j0 + jj) * 256;
                float4 w0 = W4[wbase + 0 * 64 + lane];
                float4 w1 = W4[wbase + 1 * 64 + lane];
                float4 w2 = W4[wbase + 2 * 64 + lane];
                float4 w3 = W4[wbase + 3 * 64 + lane];
                float s = 0.f;
                s = dot4(ha[0], w0, s);
                s = dot4(ha[1], w1, s);
                s = dot4(ha[2], w2, s);
                s = dot4(ha[3], w3, s);
                acc[jj] = s;
            }
            float t4v[4];
#pragma unroll
            for (int i = 0; i < 4; ++i) t4v[i] = combine2(acc[2 * i], acc[2 * i + 1], 1);
            float t2v[2];
#pragma unroll
            for (int i = 0; i < 2; ++i) t2v[i] = combine2(t4v[2 * i], t4v[2 * i + 1], 2);
            float t1 = combine2(t2v[0], t2v[1], 4);
            t1 += __shfl_xor(t1, 8, 64);
            t1 += __shfl_xor(t1, 16, 64);
            t1 += __shfl_xor(t1, 32, 64);
            if (lane < 8) {
                const int j = j0 + lane;
                lds_hs[j] = (t1 + b_h2att[j]) * C;
            }
        }
    }
    __syncthreads();

    // ---------------- Phase 2: scores -> exp*mask + sum ----------------
    {
        const float4* wa4 = (const float4*)w_alpha;
        float4 wa0 = wa4[lane], wa1 = wa4[64 + lane];
        const float4* hsl = (const float4*)lds_hs;
        float4 hs0 = hsl[lane], hs1 = hsl[64 + lane];

        float tw = wa0.x + wa0.y + wa0.z + wa0.w + wa1.x + wa1.y + wa1.z + wa1.w;
#pragma unroll
        for (int w = 1; w <= 32; w <<= 1) tw += __shfl_xor(tw, w, 64);

#pragma unroll
        for (int p = 0; p < 4; ++p) {
            const int o0 = (wv * 4 + p) * 8;
            const float4* f4 = (const float4*)att_feats
                               + ((size_t)b * OBJ + o0) * 128;

            // issue all 16 streaming loads before the transcendental chain
            float4 x[16];
#pragma unroll
            for (int oo = 0; oo < 8; ++oo) {
                x[2 * oo]     = f4[oo * 128 + lane];
                x[2 * oo + 1] = f4[oo * 128 + 64 + lane];
            }

            float acc[8];
#pragma unroll
            for (int oo = 0; oo < 8; ++oo) {
                const float4 x0 = x[2 * oo];
                const float4 x1 = x[2 * oo + 1];
                float s = 0.f;
                s = fmaf(wa0.x, __builtin_amdgcn_rcpf(exp2f(fmaf(x0.x, C, hs0.x)) + 1.0f), s);
                s = fmaf(wa0.y, __builtin_amdgcn_rcpf(exp2f(fmaf(x0.y, C, hs0.y)) + 1.0f), s);
                s = fmaf(wa0.z, __builtin_amdgcn_rcpf(exp2f(fmaf(x0.z, C, hs0.z)) + 1.0f), s);
                s = fmaf(wa0.w, __builtin_amdgcn_rcpf(exp2f(fmaf(x0.w, C, hs0.w)) + 1.0f), s);
                s = fmaf(wa1.x, __builtin_amdgcn_rcpf(exp2f(fmaf(x1.x, C, hs1.x)) + 1.0f), s);
                s = fmaf(wa1.y, __builtin_amdgcn_rcpf(exp2f(fmaf(x1.y, C, hs1.y)) + 1.0f), s);
                s = fmaf(wa1.z, __builtin_amdgcn_rcpf(exp2f(fmaf(x1.z, C, hs1.z)) + 1.0f), s);
                s = fmaf(wa1.w, __builtin_amdgcn_rcpf(exp2f(fmaf(x1.w, C, hs1.w)) + 1.0f), s);
                acc[oo] = s;
            }

            float t4v[4];
#pragma unroll
            for (int i = 0; i < 4; ++i) t4v[i] = combine2(acc[2 * i], acc[2 * i + 1], 1);
            float t2v[2];
#pragma unroll
            for (int i = 0; i < 2; ++i) t2v[i] = combine2(t4v[2 * i], t4v[2 * i + 1], 2);
            float t1 = combine2(t2v[0], t2v[1], 4);
            t1 += __shfl_xor(t1, 8, 64);
            t1 += __shfl_xor(t1, 16, 64);
            t1 += __shfl_xor(t1, 32, 64);

            float e = 0.0f;
            if (lane < 8) {
                float sc = tw - 2.0f * t1;
                float m  = (float)masks[b * OBJ + o0 + lane];
                e = __expf(sc) * m;
                ebuf[o0 + lane] = e;
            }
            float es = e;                      // lanes >= 8 contribute 0
            es += __shfl_xor(es, 1, 64);
            es += __shfl_xor(es, 2, 64);
            es += __shfl_xor(es, 4, 64);
            if (lane == 0) atomicAdd(&lds_sum, es);
        }
    }
    __syncthreads();

    // ---------------- Phase 3: normalize ----------------
    if (threadIdx.x < OBJ) {
        out[b * OBJ + threadIdx.x] = ebuf[threadIdx.x] / lds_sum;
    }
}

extern "C" void kernel_launch(void* const* d_in, const int* in_sizes, int n_in,
                              void* d_out, int out_size, void* d_ws, size_t ws_size,
                              hipStream_t stream)
{
    const float* h         = (const float*)d_in[0];
    const float* att_feats = (const float*)d_in[1];
    const int*   att_masks = (const int*)d_in[2];
    const float* W_h2att   = (const float*)d_in[3];
    const float* b_h2att   = (const float*)d_in[4];
    const float* w_alpha   = (const float*)d_in[5];
    // d_in[6] = b_alpha: constant shift, cancels exactly in softmax -> unused.

    float* out = (float*)d_out;

    fused1<<<dim3(BS), dim3(1024), 0, stream>>>(h, att_feats, att_masks,
                                                W_h2att, b_h2att, w_alpha, out);
}

// Round 6
// 218.934 us; speedup vs baseline: 1.0513x; 1.0513x over previous
//
#include <hip/hip_runtime.h>
#include <math.h>

#define BS  128
#define OBJ 512
#define RNN 1024
#define HID 512

// Merge two wave-wide partial sums (butterfly tree step).
__device__ __forceinline__ float combine2(float x, float y, int w) {
    int lane = threadIdx.x & 63;
    float send  = (lane & w) ? x : y;
    float other = __shfl_xor(send, w, 64);
    float keep  = (lane & w) ? y : x;
    return keep + other;
}

__device__ __forceinline__ float dot4(float4 a, float4 b, float s) {
    s = fmaf(a.x, b.x, s);
    s = fmaf(a.y, b.y, s);
    s = fmaf(a.z, b.z, s);
    s = fmaf(a.w, b.w, s);
    return s;
}

// K1: att_h[b,j] = sum_k h[b,k] * W[j,k]   (bias folded into K2)
// One wave computes a 2(b) x 8(j) tile via full-wave dot products.
// 4096 waves = 1024 blocks -> 16 waves/CU; W is L2-resident (2 MB).
__global__ __launch_bounds__(256, 4) void k1_h2att(
    const float* __restrict__ h, const float* __restrict__ W,
    float* __restrict__ att_h)
{
    const int lane = threadIdx.x & 63;
    const int wv   = blockIdx.x * 4 + (threadIdx.x >> 6);
    const int b0   = (wv >> 6) * 2;
    const int j0   = (wv & 63) * 8;

    const float4* h4 = (const float4*)h;   // row stride 256 float4
    const float4* W4 = (const float4*)W;   // row stride 256 float4

    float4 ha[2][4];
#pragma unroll
    for (int bi = 0; bi < 2; ++bi)
#pragma unroll
        for (int i = 0; i < 4; ++i)
            ha[bi][i] = h4[(b0 + bi) * 256 + i * 64 + lane];

    float acc[16];
#pragma unroll
    for (int jj = 0; jj < 8; ++jj) {
        const int wbase = (j0 + jj) * 256;
        float4 w0 = W4[wbase + 0 * 64 + lane];
        float4 w1 = W4[wbase + 1 * 64 + lane];
        float4 w2 = W4[wbase + 2 * 64 + lane];
        float4 w3 = W4[wbase + 3 * 64 + lane];
#pragma unroll
        for (int bi = 0; bi < 2; ++bi) {
            float s = 0.f;
            s = dot4(ha[bi][0], w0, s);
            s = dot4(ha[bi][1], w1, s);
            s = dot4(ha[bi][2], w2, s);
            s = dot4(ha[bi][3], w3, s);
            acc[jj * 2 + bi] = s;   // idx bit0 = bi, bits1-3 = jj
        }
    }

    float t8[8];
#pragma unroll
    for (int i = 0; i < 8; ++i) t8[i] = combine2(acc[2 * i], acc[2 * i + 1], 1);
    float t4v[4];
#pragma unroll
    for (int i = 0; i < 4; ++i) t4v[i] = combine2(t8[2 * i], t8[2 * i + 1], 2);
    float t2v[2];
#pragma unroll
    for (int i = 0; i < 2; ++i) t2v[i] = combine2(t4v[2 * i], t4v[2 * i + 1], 4);
    float t1 = combine2(t2v[0], t2v[1], 8);
    t1 += __shfl_xor(t1, 16, 64);
    t1 += __shfl_xor(t1, 32, 64);

    if (lane < 16) {
        int bi = lane & 1;
        int jj = lane >> 1;
        att_h[(b0 + bi) * HID + j0 + jj] = t1;
    }
}

// K2: scores[b,o] = sum_h w_alpha[h] * tanh(att_feats[b,o,h] + att_h[b,h] + b_h2att[h])
// tanh(x) = 1 - 2/(1+e^{2x});  score = sum(w) - 2*sum(w * rcp(exp2(C*f + hs)+1)),
// C = 2*log2(e).  b_alpha dropped (constant shift cancels in softmax).
//
// Latency hiding comes from TLP, not ILP: __launch_bounds__(256,8) caps VGPRs
// at 64 so 8 waves/SIMD (32/CU) are resident; per-oo load pairs are covered by
// the other waves' issue work.  8192 waves = 2048 blocks.
__global__ __launch_bounds__(256, 8) void k2_scores(
    const float* __restrict__ att_feats, const float* __restrict__ att_h,
    const float* __restrict__ b_h2att, const float* __restrict__ w_alpha,
    float* __restrict__ scores)
{
    const int lane = threadIdx.x & 63;
    const int wv   = blockIdx.x * 4 + (threadIdx.x >> 6);
    const int b    = wv >> 6;
    const int o0   = (wv & 63) * 8;

    const float C = 2.8853900817779268f;   // 2*log2(e)
    const float4* ah4 = (const float4*)(att_h + b * HID);
    const float4* bb4 = (const float4*)b_h2att;
    const float4* wa4 = (const float4*)w_alpha;

    float4 a0 = ah4[lane],  a1 = ah4[64 + lane];
    float4 c0 = bb4[lane],  c1 = bb4[64 + lane];
    float4 wa0 = wa4[lane], wa1 = wa4[64 + lane];

    float4 hs0, hs1;   // (att_h + bias) * C, pre-scaled for exp2
    hs0.x = (a0.x + c0.x) * C; hs0.y = (a0.y + c0.y) * C;
    hs0.z = (a0.z + c0.z) * C; hs0.w = (a0.w + c0.w) * C;
    hs1.x = (a1.x + c1.x) * C; hs1.y = (a1.y + c1.y) * C;
    hs1.z = (a1.z + c1.z) * C; hs1.w = (a1.w + c1.w) * C;

    float wsum = wa0.x + wa0.y + wa0.z + wa0.w + wa1.x + wa1.y + wa1.z + wa1.w;

    const float4* f4 = (const float4*)att_feats + (size_t)(b * OBJ + o0) * 128;

    float acc[8];
#pragma unroll
    for (int oo = 0; oo < 8; ++oo) {
        const float4 x0 = f4[oo * 128 + lane];
        const float4 x1 = f4[oo * 128 + 64 + lane];
        float s = 0.f;
        s = fmaf(wa0.x, __builtin_amdgcn_rcpf(exp2f(fmaf(x0.x, C, hs0.x)) + 1.0f), s);
        s = fmaf(wa0.y, __builtin_amdgcn_rcpf(exp2f(fmaf(x0.y, C, hs0.y)) + 1.0f), s);
        s = fmaf(wa0.z, __builtin_amdgcn_rcpf(exp2f(fmaf(x0.z, C, hs0.z)) + 1.0f), s);
        s = fmaf(wa0.w, __builtin_amdgcn_rcpf(exp2f(fmaf(x0.w, C, hs0.w)) + 1.0f), s);
        s = fmaf(wa1.x, __builtin_amdgcn_rcpf(exp2f(fmaf(x1.x, C, hs1.x)) + 1.0f), s);
        s = fmaf(wa1.y, __builtin_amdgcn_rcpf(exp2f(fmaf(x1.y, C, hs1.y)) + 1.0f), s);
        s = fmaf(wa1.z, __builtin_amdgcn_rcpf(exp2f(fmaf(x1.z, C, hs1.z)) + 1.0f), s);
        s = fmaf(wa1.w, __builtin_amdgcn_rcpf(exp2f(fmaf(x1.w, C, hs1.w)) + 1.0f), s);
        acc[oo] = s;
    }

    // reduce: 8 accumulators -> lanes 0..7 hold sum(w*r) per object
    float t4v[4];
#pragma unroll
    for (int i = 0; i < 4; ++i) t4v[i] = combine2(acc[2 * i], acc[2 * i + 1], 1);
    float t2v[2];
#pragma unroll
    for (int i = 0; i < 2; ++i) t2v[i] = combine2(t4v[2 * i], t4v[2 * i + 1], 2);
    float t1 = combine2(t2v[0], t2v[1], 4);
    t1 += __shfl_xor(t1, 8, 64);
    t1 += __shfl_xor(t1, 16, 64);
    t1 += __shfl_xor(t1, 32, 64);

    // total sum of w_alpha across all 512 h (same for every object)
    float tw = wsum;
#pragma unroll
    for (int w = 1; w <= 32; w <<= 1) tw += __shfl_xor(tw, w, 64);

    if (lane < 8) scores[b * OBJ + o0 + lane] = tw - 2.0f * t1;
}

// K3: weight = e*m / sum(e*m), e = exp(s - max(s)).  In-place in d_out.
__global__ __launch_bounds__(256) void k3_softmax(
    float* __restrict__ scores_out, const int* __restrict__ masks)
{
    __shared__ float red[4];
    const int b    = blockIdx.x;
    const int t    = threadIdx.x;
    const int lane = t & 63;
    const int wv   = t >> 6;

    float s0 = scores_out[b * OBJ + t];
    float s1 = scores_out[b * OBJ + t + 256];
    float m0 = (float)masks[b * OBJ + t];
    float m1 = (float)masks[b * OBJ + t + 256];

    float mx = fmaxf(s0, s1);
#pragma unroll
    for (int w = 1; w <= 32; w <<= 1) mx = fmaxf(mx, __shfl_xor(mx, w, 64));
    if (lane == 0) red[wv] = mx;
    __syncthreads();
    mx = fmaxf(fmaxf(red[0], red[1]), fmaxf(red[2], red[3]));
    __syncthreads();

    float e0 = __expf(s0 - mx) * m0;
    float e1 = __expf(s1 - mx) * m1;
    float sm = e0 + e1;
#pragma unroll
    for (int w = 1; w <= 32; w <<= 1) sm += __shfl_xor(sm, w, 64);
    if (lane == 0) red[wv] = sm;
    __syncthreads();
    sm = (red[0] + red[1]) + (red[2] + red[3]);

    float inv = 1.0f / sm;
    scores_out[b * OBJ + t]       = e0 * inv;
    scores_out[b * OBJ + t + 256] = e1 * inv;
}

extern "C" void kernel_launch(void* const* d_in, const int* in_sizes, int n_in,
                              void* d_out, int out_size, void* d_ws, size_t ws_size,
                              hipStream_t stream)
{
    const float* h         = (const float*)d_in[0];
    const float* att_feats = (const float*)d_in[1];
    const int*   att_masks = (const int*)d_in[2];
    const float* W_h2att   = (const float*)d_in[3];
    const float* b_h2att   = (const float*)d_in[4];
    const float* w_alpha   = (const float*)d_in[5];
    // d_in[6] = b_alpha: constant shift, cancels exactly in softmax -> unused.

    float* att_h  = (float*)d_ws;        // BS*HID floats = 256 KB scratch
    float* scores = (float*)d_out;       // exactly BS*OBJ floats; K3 runs in-place

    k1_h2att  <<<dim3(1024), dim3(256), 0, stream>>>(h, W_h2att, att_h);
    k2_scores <<<dim3(2048), dim3(256), 0, stream>>>(att_feats, att_h, b_h2att,
                                                     w_alpha, scores);
    k3_softmax<<<dim3(BS),   dim3(256), 0, stream>>>(scores, att_masks);
}

// Round 9
// 209.299 us; speedup vs baseline: 1.0997x; 1.0460x over previous
//
#include <hip/hip_runtime.h>
#include <math.h>

#define BS  128
#define OBJ 512
#define RNN 1024
#define HID 512

// clang native vector type: __builtin_nontemporal_load requires a pointer to
// scalar or native vector (HIP_vector_type float4 is a struct -> rejected).
typedef float nfloat4 __attribute__((ext_vector_type(4)));

// Merge two wave-wide partial sums (butterfly tree step).
__device__ __forceinline__ float combine2(float x, float y, int w) {
    int lane = threadIdx.x & 63;
    float send  = (lane & w) ? x : y;
    float other = __shfl_xor(send, w, 64);
    float keep  = (lane & w) ? y : x;
    return keep + other;
}

__device__ __forceinline__ float dot4(float4 a, float4 b, float s) {
    s = fmaf(a.x, b.x, s);
    s = fmaf(a.y, b.y, s);
    s = fmaf(a.z, b.z, s);
    s = fmaf(a.w, b.w, s);
    return s;
}

// K1: att_h[b,j] = sum_k h[b,k] * W[j,k]   (bias folded into K2)
// One wave computes a 2(b) x 8(j) tile via full-wave dot products.
__global__ __launch_bounds__(256, 4) void k1_h2att(
    const float* __restrict__ h, const float* __restrict__ W,
    float* __restrict__ att_h)
{
    const int lane = threadIdx.x & 63;
    const int wv   = blockIdx.x * 4 + (threadIdx.x >> 6);
    const int b0   = (wv >> 6) * 2;
    const int j0   = (wv & 63) * 8;

    const float4* h4 = (const float4*)h;   // row stride 256 float4
    const float4* W4 = (const float4*)W;   // row stride 256 float4

    float4 ha[2][4];
#pragma unroll
    for (int bi = 0; bi < 2; ++bi)
#pragma unroll
        for (int i = 0; i < 4; ++i)
            ha[bi][i] = h4[(b0 + bi) * 256 + i * 64 + lane];

    float acc[16];
#pragma unroll
    for (int jj = 0; jj < 8; ++jj) {
        const int wbase = (j0 + jj) * 256;
        float4 w0 = W4[wbase + 0 * 64 + lane];
        float4 w1 = W4[wbase + 1 * 64 + lane];
        float4 w2 = W4[wbase + 2 * 64 + lane];
        float4 w3 = W4[wbase + 3 * 64 + lane];
#pragma unroll
        for (int bi = 0; bi < 2; ++bi) {
            float s = 0.f;
            s = dot4(ha[bi][0], w0, s);
            s = dot4(ha[bi][1], w1, s);
            s = dot4(ha[bi][2], w2, s);
            s = dot4(ha[bi][3], w3, s);
            acc[jj * 2 + bi] = s;   // idx bit0 = bi, bits1-3 = jj
        }
    }

    float t8[8];
#pragma unroll
    for (int i = 0; i < 8; ++i) t8[i] = combine2(acc[2 * i], acc[2 * i + 1], 1);
    float t4v[4];
#pragma unroll
    for (int i = 0; i < 4; ++i) t4v[i] = combine2(t8[2 * i], t8[2 * i + 1], 2);
    float t2v[2];
#pragma unroll
    for (int i = 0; i < 2; ++i) t2v[i] = combine2(t4v[2 * i], t4v[2 * i + 1], 4);
    float t1 = combine2(t2v[0], t2v[1], 8);
    t1 += __shfl_xor(t1, 16, 64);
    t1 += __shfl_xor(t1, 32, 64);

    if (lane < 16) {
        int bi = lane & 1;
        int jj = lane >> 1;
        att_h[(b0 + bi) * HID + j0 + jj] = t1;
    }
}

// K2: scores[b,o] = sum_h w_alpha[h] * tanh(att_feats[b,o,h] + att_h[b,h] + b_h2att[h])
// tanh(x) = 1 - 2/(1+e^{2x});  score = sum(w) - 2*sum(w * rcp(exp2(C*f + hs)+1)),
// C = 2*log2(e).  b_alpha dropped (constant shift cancels in softmax).
//
// att_feats is a 134 MB read-once stream that the harness re-writes (restore)
// immediately before every timed run; the standard cached-read path for that
// just-written data measured ~2.2 TB/s across three structurally different
// variants.  This round: NON-TEMPORAL loads for the stream (nt cache policy),
// all 16 dwordx4 issued before the transcendental chain ((256,4) -> VGPR cap
// 128, fits the x[16] batch).
__global__ __launch_bounds__(256, 4) void k2_scores(
    const float* __restrict__ att_feats, const float* __restrict__ att_h,
    const float* __restrict__ b_h2att, const float* __restrict__ w_alpha,
    float* __restrict__ scores)
{
    const int lane = threadIdx.x & 63;
    const int wv   = blockIdx.x * 4 + (threadIdx.x >> 6);
    const int b    = wv >> 6;
    const int o0   = (wv & 63) * 8;

    const nfloat4* f4 = (const nfloat4*)att_feats + (size_t)(b * OBJ + o0) * 128;

    // ---- issue all streaming loads first (16 x dwordx4, non-temporal) ----
    nfloat4 x[16];
#pragma unroll
    for (int oo = 0; oo < 8; ++oo) {
        x[2 * oo]     = __builtin_nontemporal_load(&f4[oo * 128 + lane]);
        x[2 * oo + 1] = __builtin_nontemporal_load(&f4[oo * 128 + 64 + lane]);
    }

    // ---- hoisted per-wave vectors (cached, reused by all waves) ----
    const float C = 2.8853900817779268f;   // 2*log2(e)
    const float4* ah4 = (const float4*)(att_h + b * HID);
    const float4* bb4 = (const float4*)b_h2att;
    const float4* wa4 = (const float4*)w_alpha;

    float4 a0 = ah4[lane],  a1 = ah4[64 + lane];
    float4 c0 = bb4[lane],  c1 = bb4[64 + lane];
    float4 wa0 = wa4[lane], wa1 = wa4[64 + lane];

    float4 hs0, hs1;   // (att_h + bias) * C, pre-scaled for exp2
    hs0.x = (a0.x + c0.x) * C; hs0.y = (a0.y + c0.y) * C;
    hs0.z = (a0.z + c0.z) * C; hs0.w = (a0.w + c0.w) * C;
    hs1.x = (a1.x + c1.x) * C; hs1.y = (a1.y + c1.y) * C;
    hs1.z = (a1.z + c1.z) * C; hs1.w = (a1.w + c1.w) * C;

    float wsum = wa0.x + wa0.y + wa0.z + wa0.w + wa1.x + wa1.y + wa1.z + wa1.w;

    // ---- per-element: acc += w * rcp(exp2(fma(f, C, hs)) + 1) ----
    float acc[8];
#pragma unroll
    for (int oo = 0; oo < 8; ++oo) {
        const nfloat4 x0 = x[2 * oo];
        const nfloat4 x1 = x[2 * oo + 1];
        float s = 0.f;
        s = fmaf(wa0.x, __builtin_amdgcn_rcpf(exp2f(fmaf(x0.x, C, hs0.x)) + 1.0f), s);
        s = fmaf(wa0.y, __builtin_amdgcn_rcpf(exp2f(fmaf(x0.y, C, hs0.y)) + 1.0f), s);
        s = fmaf(wa0.z, __builtin_amdgcn_rcpf(exp2f(fmaf(x0.z, C, hs0.z)) + 1.0f), s);
        s = fmaf(wa0.w, __builtin_amdgcn_rcpf(exp2f(fmaf(x0.w, C, hs0.w)) + 1.0f), s);
        s = fmaf(wa1.x, __builtin_amdgcn_rcpf(exp2f(fmaf(x1.x, C, hs1.x)) + 1.0f), s);
        s = fmaf(wa1.y, __builtin_amdgcn_rcpf(exp2f(fmaf(x1.y, C, hs1.y)) + 1.0f), s);
        s = fmaf(wa1.z, __builtin_amdgcn_rcpf(exp2f(fmaf(x1.z, C, hs1.z)) + 1.0f), s);
        s = fmaf(wa1.w, __builtin_amdgcn_rcpf(exp2f(fmaf(x1.w, C, hs1.w)) + 1.0f), s);
        acc[oo] = s;
    }

    // ---- reduce: 8 accumulators -> lanes 0..7 hold sum(w*r) per object ----
    float t4v[4];
#pragma unroll
    for (int i = 0; i < 4; ++i) t4v[i] = combine2(acc[2 * i], acc[2 * i + 1], 1);
    float t2v[2];
#pragma unroll
    for (int i = 0; i < 2; ++i) t2v[i] = combine2(t4v[2 * i], t4v[2 * i + 1], 2);
    float t1 = combine2(t2v[0], t2v[1], 4);
    t1 += __shfl_xor(t1, 8, 64);
    t1 += __shfl_xor(t1, 16, 64);
    t1 += __shfl_xor(t1, 32, 64);

    // total sum of w_alpha across all 512 h (same for every object)
    float tw = wsum;
#pragma unroll
    for (int w = 1; w <= 32; w <<= 1) tw += __shfl_xor(tw, w, 64);

    if (lane < 8)
        scores[b * OBJ + o0 + lane] = tw - 2.0f * t1;
}

// K3: weight = e*m / sum(e*m), e = exp(s - max(s)).  In-place in d_out.
__global__ __launch_bounds__(256) void k3_softmax(
    float* __restrict__ scores_out, const int* __restrict__ masks)
{
    __shared__ float red[4];
    const int b    = blockIdx.x;
    const int t    = threadIdx.x;
    const int lane = t & 63;
    const int wv   = t >> 6;

    float s0 = scores_out[b * OBJ + t];
    float s1 = scores_out[b * OBJ + t + 256];
    float m0 = (float)masks[b * OBJ + t];
    float m1 = (float)masks[b * OBJ + t + 256];

    float mx = fmaxf(s0, s1);
#pragma unroll
    for (int w = 1; w <= 32; w <<= 1) mx = fmaxf(mx, __shfl_xor(mx, w, 64));
    if (lane == 0) red[wv] = mx;
    __syncthreads();
    mx = fmaxf(fmaxf(red[0], red[1]), fmaxf(red[2], red[3]));
    __syncthreads();

    float e0 = __expf(s0 - mx) * m0;
    float e1 = __expf(s1 - mx) * m1;
    float sm = e0 + e1;
#pragma unroll
    for (int w = 1; w <= 32; w <<= 1) sm += __shfl_xor(sm, w, 64);
    if (lane == 0) red[wv] = sm;
    __syncthreads();
    sm = (red[0] + red[1]) + (red[2] + red[3]);

    float inv = 1.0f / sm;
    scores_out[b * OBJ + t]       = e0 * inv;
    scores_out[b * OBJ + t + 256] = e1 * inv;
}

extern "C" void kernel_launch(void* const* d_in, const int* in_sizes, int n_in,
                              void* d_out, int out_size, void* d_ws, size_t ws_size,
                              hipStream_t stream)
{
    const float* h         = (const float*)d_in[0];
    const float* att_feats = (const float*)d_in[1];
    const int*   att_masks = (const int*)d_in[2];
    const float* W_h2att   = (const float*)d_in[3];
    const float* b_h2att   = (const float*)d_in[4];
    const float* w_alpha   = (const float*)d_in[5];
    // d_in[6] = b_alpha: constant shift, cancels exactly in softmax -> unused.

    float* att_h  = (float*)d_ws;        // BS*HID floats = 256 KB scratch
    float* scores = (float*)d_out;       // exactly BS*OBJ floats; K3 runs in-place

    k1_h2att  <<<dim3(1024), dim3(256), 0, stream>>>(h, W_h2att, att_h);
    k2_scores <<<dim3(2048), dim3(256), 0, stream>>>(att_feats, att_h, b_h2att,
                                                     w_alpha, scores);
    k3_softmax<<<dim3(BS),   dim3(256), 0, stream>>>(scores, att_masks);
}